// Round 9
// baseline (965.312 us; speedup 1.0000x reference)
//
#include <hip/hip_runtime.h>
#include <hip/hip_bf16.h>

#define N_NODES 100000
#define N_EDGES 1600000
#define DIM 128
#define N_RATES 5
#define OUT_W (N_RATES * DIM)          // 640
#define PK_SHIFT 17                     // src < 2^17, rate in bits 17..19
#define PK_MASK  0x1FFFF
#define SCAN_NB ((N_NODES + 1023) / 1024)   // 98
#define MT_TILES ((N_NODES + 63) / 64)      // 1563

// ---- workspace layout (bytes) ----
#define WS_DEG_OUT 0x000000u   // int[5N]  2 MB
#define WS_DEG_IN  0x200000u   // int[5N]  2 MB
#define WS_NSRC    0x400000u   // f32[5N]  2 MB
#define WS_NDST    0x600000u   // f32[5N]  2 MB
#define WS_OFFS    0x800000u   // int[N]   400 KB
#define WS_CURSOR  0x880000u   // int[N]   400 KB
#define WS_BSUM    0x900000u   // int[98]
#define WS_PACKED  0xA00000u   // int[E]   6.4 MB (ends 0x101A800)
#define WS_G       0x1100000u  // agg slots: [slot][N][256] bf16 bits (hi|lo)
#define SLOT_BYTES ((size_t)N_NODES * 256 * sizeof(unsigned short))  // 51.2 MB

typedef float f4     __attribute__((ext_vector_type(4)));
typedef short bf16x8 __attribute__((ext_vector_type(8)));   // 8 bf16 bit-patterns

// ---------------------------------------------------------------------------
// Per-(rate,node) degree histograms (int atomics into zeroed ws).
// ---------------------------------------------------------------------------
__global__ __launch_bounds__(256) void deg_kernel(const int* __restrict__ src,
                                                  const int* __restrict__ dst,
                                                  const int* __restrict__ rate,
                                                  int* __restrict__ deg_out,
                                                  int* __restrict__ deg_in) {
    int e = blockIdx.x * 256 + threadIdx.x;
    if (e >= N_EDGES) return;
    int r = rate[e];
    atomicAdd(&deg_out[r * N_NODES + src[e]], 1);
    atomicAdd(&deg_in [r * N_NODES + dst[e]], 1);
}

// ---------------------------------------------------------------------------
// norm = max(deg,1)^-0.5 for all (rate,node).
// ---------------------------------------------------------------------------
__global__ __launch_bounds__(256) void norm_kernel(const int* __restrict__ deg_out,
                                                   const int* __restrict__ deg_in,
                                                   float* __restrict__ nsrc,
                                                   float* __restrict__ ndst) {
    int i = blockIdx.x * 256 + threadIdx.x;
    if (i >= N_RATES * N_NODES) return;
    int d0 = deg_out[i]; if (d0 < 1) d0 = 1;
    int d1 = deg_in[i];  if (d1 < 1) d1 = 1;
    nsrc[i] = 1.0f / sqrtf((float)d0);
    ndst[i] = 1.0f / sqrtf((float)d1);
}

// ---------------------------------------------------------------------------
// Exclusive scan of per-dst total in-degree (sum over 5 rate rows of deg_in).
// ---------------------------------------------------------------------------
__global__ __launch_bounds__(256) void scan1_kernel(const int* __restrict__ deg_in,
                                                    int* __restrict__ offs,
                                                    int* __restrict__ bsum) {
    __shared__ int sh[256];
    int tid = threadIdx.x;
    int base = blockIdx.x * 1024 + tid * 4;
    int v[4];
#pragma unroll
    for (int j = 0; j < 4; ++j) {
        int idx = base + j, s = 0;
        if (idx < N_NODES) {
#pragma unroll
            for (int r = 0; r < N_RATES; ++r) s += deg_in[r * N_NODES + idx];
        }
        v[j] = s;
    }
    int tsum = v[0] + v[1] + v[2] + v[3];
    sh[tid] = tsum;
    __syncthreads();
    for (int off = 1; off < 256; off <<= 1) {
        int t = (tid >= off) ? sh[tid - off] : 0;
        __syncthreads();
        sh[tid] += t;
        __syncthreads();
    }
    int excl = sh[tid] - tsum;
#pragma unroll
    for (int j = 0; j < 4; ++j) {
        int idx = base + j;
        if (idx < N_NODES) offs[idx] = excl;
        excl += v[j];
    }
    if (tid == 255) bsum[blockIdx.x] = sh[255];
}

__global__ void scan2_kernel(int* __restrict__ bsum) {
    if (threadIdx.x != 0 || blockIdx.x != 0) return;
    int run = 0;
    for (int i = 0; i < SCAN_NB; ++i) { int t = bsum[i]; bsum[i] = run; run += t; }
}

__global__ __launch_bounds__(256) void scan3_kernel(int* __restrict__ offs,
                                                    const int* __restrict__ bsum,
                                                    int* __restrict__ cursor) {
    int i = blockIdx.x * 256 + threadIdx.x;
    if (i >= N_NODES) return;
    int v = offs[i] + bsum[i >> 10];
    offs[i] = v;
    cursor[i] = v;
}

// ---------------------------------------------------------------------------
// CSR fill: packed[pos] = src | (rate<<17), bucketed by dst via atomic cursor.
// ---------------------------------------------------------------------------
__global__ __launch_bounds__(256) void fill_kernel(const int* __restrict__ src,
                                                   const int* __restrict__ dst,
                                                   const int* __restrict__ rate,
                                                   int* __restrict__ cursor,
                                                   int* __restrict__ packed) {
    int e = blockIdx.x * 256 + threadIdx.x;
    if (e >= N_EDGES) return;
    int pos = atomicAdd(&cursor[dst[e]], 1);
    packed[pos] = src[e] | (rate[e] << PK_SHIFT);
}

// ---------------------------------------------------------------------------
// Gather (aggregate-first): one wave per dst, unroll-4 load/accumulate split.
// acc[r] += h[src]*nsrc[r][src] for rates in [rbase, rbase+GS).
// Epilogue stores agg row as bf16 hi|lo planes ([d][0:128]=hi, [128:256]=lo).
// h table is 51.2 MB -> L3-resident. No float atomics anywhere.
// ---------------------------------------------------------------------------
template<int GS, bool ALL>
__global__ __launch_bounds__(256) void gather_kernel(const float* __restrict__ h,
                                                     const int* __restrict__ packed,
                                                     const int* __restrict__ offs,
                                                     const float* __restrict__ nsrc,
                                                     unsigned short* __restrict__ agg,
                                                     int rbase) {
    int gw   = (blockIdx.x * 256 + threadIdx.x) >> 6;  // wave id == dst
    int lane = threadIdx.x & 63;
    if (gw >= N_NODES) return;
    const int d = gw;
    int beg = offs[d];
    int end = (d == N_NODES - 1) ? N_EDGES : offs[d + 1];

    float2 a0 = make_float2(0.f, 0.f), a1 = a0, a2 = a0, a3 = a0, a4 = a0;

    int p = beg;
    for (; p + 4 <= end; p += 4) {
        int pk[4]; int rl[4]; bool use[4]; float2 v[4]; float ns[4];
#pragma unroll
        for (int i = 0; i < 4; ++i) pk[i] = packed[p + i];
#pragma unroll
        for (int i = 0; i < 4; ++i) {
            rl[i]  = (pk[i] >> PK_SHIFT) - rbase;
            use[i] = ALL || ((unsigned)rl[i] < (unsigned)GS);
        }
#pragma unroll
        for (int i = 0; i < 4; ++i) {
            int s = pk[i] & PK_MASK;
            if (use[i]) {
                v[i]  = *(const float2*)(h + (size_t)s * DIM + lane * 2);
                ns[i] = nsrc[(size_t)(rl[i] + rbase) * N_NODES + s];
            }
        }
#pragma unroll
        for (int i = 0; i < 4; ++i) {
            if (!use[i]) continue;
            float tx = v[i].x * ns[i], ty = v[i].y * ns[i];
            switch (rl[i]) {
                case 0: a0.x += tx; a0.y += ty; break;
                case 1: if constexpr (GS > 1) { a1.x += tx; a1.y += ty; } break;
                case 2: if constexpr (GS > 2) { a2.x += tx; a2.y += ty; } break;
                case 3: if constexpr (GS > 3) { a3.x += tx; a3.y += ty; } break;
                default: if constexpr (GS > 4) { a4.x += tx; a4.y += ty; } break;
            }
        }
    }
    for (; p < end; ++p) {
        int pkx = packed[p];
        int rlx = (pkx >> PK_SHIFT) - rbase;
        if (!ALL && (unsigned)rlx >= (unsigned)GS) continue;
        int s = pkx & PK_MASK;
        float2 v = *(const float2*)(h + (size_t)s * DIM + lane * 2);
        float ns = nsrc[(size_t)(rlx + rbase) * N_NODES + s];
        float tx = v.x * ns, ty = v.y * ns;
        switch (rlx) {
            case 0: a0.x += tx; a0.y += ty; break;
            case 1: if constexpr (GS > 1) { a1.x += tx; a1.y += ty; } break;
            case 2: if constexpr (GS > 2) { a2.x += tx; a2.y += ty; } break;
            case 3: if constexpr (GS > 3) { a3.x += tx; a3.y += ty; } break;
            default: if constexpr (GS > 4) { a4.x += tx; a4.y += ty; } break;
        }
    }

    // epilogue: split each f32 into bf16 hi (RNE) + bf16 lo (x - hi)
#pragma unroll
    for (int ri = 0; ri < GS; ++ri) {
        float2 acc = (ri == 0) ? a0 : (ri == 1) ? a1 : (ri == 2) ? a2
                   : (ri == 3) ? a3 : a4;
        unsigned short* row = agg + ((size_t)ri * N_NODES + d) * 256;
        __bf16 hx = (__bf16)acc.x; __bf16 lx = (__bf16)(acc.x - (float)hx);
        __bf16 hy = (__bf16)acc.y; __bf16 ly = (__bf16)(acc.y - (float)hy);
        unsigned int hv = (unsigned int)__builtin_bit_cast(unsigned short, hx)
                        | ((unsigned int)__builtin_bit_cast(unsigned short, hy) << 16);
        unsigned int lv = (unsigned int)__builtin_bit_cast(unsigned short, lx)
                        | ((unsigned int)__builtin_bit_cast(unsigned short, ly) << 16);
        *(unsigned int*)(row + lane * 2)       = hv;
        *(unsigned int*)(row + 128 + lane * 2) = lv;
    }
}

// ---------------------------------------------------------------------------
// MFMA GEMM: out[:, r*128:(r+1)*128] = (agg[r] @ W[r]) * nd[r] + b[r]
// bf16 hi/lo 3-product split (error ~2^-16, ~f32 quality). W[r] transposed +
// split into padded LDS once per block; grid-stride over 64-row M-tiles.
// A-frags loaded straight from global agg planes (each byte read once).
// Layouts (16x16x32_bf16, m89/m91-verified): A row=l&15, k=(l>>4)*8+j;
// B col=l&15, same k (via transposed LDS rows); D col=l&15, row=(l>>4)*4+q.
// ---------------------------------------------------------------------------
__global__ __launch_bounds__(256) void gemm_agg_kernel(const unsigned short* __restrict__ agg,
                                                       const float* __restrict__ Wall,
                                                       const float* __restrict__ bias,
                                                       const float* __restrict__ ndst,
                                                       float* __restrict__ out,
                                                       int rbase) {
    __shared__ __align__(16) unsigned short sWt[2][128][136];  // 69.6 KB, pitch 272B
    const int slot = blockIdx.y;
    const int r = rbase + slot;
    const float* Wr = Wall + (size_t)r * DIM * DIM;
    const int tid = threadIdx.x;

    // stage W[r]: read [k][n] coalesced f32, write hi/lo bf16 transposed [n][k]
#pragma unroll
    for (int phase = 0; phase < 16; ++phase) {
        int f = phase * 1024 + tid * 4;      // flat f32 idx, f = k*128 + n
        int k = f >> 7, n = f & 127;
        float4 w4 = *(const float4*)(Wr + f);
        float wv[4] = {w4.x, w4.y, w4.z, w4.w};
#pragma unroll
        for (int j = 0; j < 4; ++j) {
            __bf16 hb = (__bf16)wv[j];
            __bf16 lb = (__bf16)(wv[j] - (float)hb);
            sWt[0][n + j][k] = __builtin_bit_cast(unsigned short, hb);
            sWt[1][n + j][k] = __builtin_bit_cast(unsigned short, lb);
        }
    }
    __syncthreads();

    const int w = tid >> 6, l = tid & 63;
    const int lrow = l & 15;            // A row / B col / D col within tile
    const int lk   = (l >> 4) * 8;      // K offset within 32-chunk
    const int lq4  = (l >> 4) * 4;      // D row group
    const float* ndr = ndst + (size_t)r * N_NODES;
    const float* br  = bias + (size_t)r * DIM;

    for (int mt = blockIdx.x; mt < MT_TILES; mt += gridDim.x) {
        int rowA = mt * 64 + w * 16 + lrow;
        int rowAc = rowA < N_NODES ? rowA : 0;      // clamp; garbage rows masked at store
        const unsigned short* arow = agg + ((size_t)slot * N_NODES + rowAc) * 256;

        f4 acc[8];
#pragma unroll
        for (int i = 0; i < 8; ++i) acc[i] = (f4){0.f, 0.f, 0.f, 0.f};

#pragma unroll
        for (int ks = 0; ks < 4; ++ks) {
            int k0 = ks * 32;
            bf16x8 ah = *(const bf16x8*)(arow + k0 + lk);         // hi plane
            bf16x8 al = *(const bf16x8*)(arow + 128 + k0 + lk);   // lo plane
#pragma unroll
            for (int nt = 0; nt < 8; ++nt) {
                bf16x8 bh = *(const bf16x8*)&sWt[0][nt * 16 + lrow][k0 + lk];
                bf16x8 bl = *(const bf16x8*)&sWt[1][nt * 16 + lrow][k0 + lk];
                acc[nt] = __builtin_amdgcn_mfma_f32_16x16x32_bf16(ah, bh, acc[nt], 0, 0, 0);
                acc[nt] = __builtin_amdgcn_mfma_f32_16x16x32_bf16(ah, bl, acc[nt], 0, 0, 0);
                acc[nt] = __builtin_amdgcn_mfma_f32_16x16x32_bf16(al, bh, acc[nt], 0, 0, 0);
            }
        }

        int rowD0 = mt * 64 + w * 16 + lq4;
#pragma unroll
        for (int q = 0; q < 4; ++q) {
            int row = rowD0 + q;
            if (row < N_NODES) {
                float ndv = ndr[row];
                float* orow = out + (size_t)row * OUT_W + r * DIM;
#pragma unroll
                for (int nt = 0; nt < 8; ++nt) {
                    int col = nt * 16 + lrow;
                    orow[col] = acc[nt][q] * ndv + br[col];
                }
            }
        }
    }
}

// ===========================================================================
// Minimal-ws fallback (needs only 8 MB): scatter h*ns into out (atomics),
// then in-place per-tile f32 GEMM with norm+bias epilogue.
// ===========================================================================
__global__ __launch_bounds__(256) void zero_out_kernel(float4* __restrict__ out) {
    int i = blockIdx.x * 256 + threadIdx.x;
    if (i < N_NODES * OUT_W / 4) out[i] = make_float4(0.f, 0.f, 0.f, 0.f);
}

__global__ __launch_bounds__(256) void scatter_c_kernel(const float* __restrict__ h,
                                                        const int* __restrict__ src,
                                                        const int* __restrict__ dst,
                                                        const int* __restrict__ rate,
                                                        const float* __restrict__ nsrc,
                                                        float* __restrict__ out) {
    int lane = threadIdx.x & 63;
    int gw = (blockIdx.x * 256 + threadIdx.x) >> 6;
    int e0 = gw * 4;
#pragma unroll
    for (int i = 0; i < 4; ++i) {
        int e = e0 + i;
        if (e >= N_EDGES) return;
        int s = src[e], d = dst[e], r = rate[e];
        float ns = nsrc[(size_t)r * N_NODES + s];
        float2 v = *(const float2*)(h + (size_t)s * DIM + lane * 2);
        float* o = out + (size_t)d * OUT_W + r * DIM + lane * 2;
        unsafeAtomicAdd(o,     v.x * ns);
        unsafeAtomicAdd(o + 1, v.y * ns);
    }
}

__global__ __launch_bounds__(256) void gemm_inplace_kernel(float* __restrict__ outp,
                                                           const float* __restrict__ Wall,
                                                           const float* __restrict__ bias,
                                                           const float* __restrict__ ndst,
                                                           int r) {
    __shared__ float sW[32][128];
    __shared__ float sA[32][64];
    float* A = outp + r * DIM;
    const float* Wr = Wall + (size_t)r * DIM * DIM;
    const float* nd = ndst + (size_t)r * N_NODES;
    const float* br = bias + (size_t)r * DIM;
    int tid  = threadIdx.x;
    int row0 = blockIdx.x * 64;
    int c2   = (tid & 63) * 2;
    int rg   = tid >> 6;
    int rb   = rg * 16;
    float acc0[16], acc1[16];
#pragma unroll
    for (int i = 0; i < 16; ++i) { acc0[i] = 0.f; acc1[i] = 0.f; }
    for (int kc = 0; kc < 128; kc += 32) {
        __syncthreads();
#pragma unroll
        for (int j = 0; j < 4; ++j) {
            int f = tid * 4 + j * 1024;
            int kl = f >> 7, c = f & 127;
            *(float4*)(&sW[kl][c]) = *(const float4*)(Wr + (kc + kl) * 128 + c);
        }
#pragma unroll
        for (int j = 0; j < 2; ++j) {
            int f = tid * 4 + j * 1024;
            int rowl = f >> 5, kl = f & 31;
            int grow = row0 + rowl;
            float4 a4 = make_float4(0.f, 0.f, 0.f, 0.f);
            if (grow < N_NODES) a4 = *(const float4*)(A + (size_t)grow * OUT_W + kc + kl);
            sA[kl + 0][rowl] = a4.x; sA[kl + 1][rowl] = a4.y;
            sA[kl + 2][rowl] = a4.z; sA[kl + 3][rowl] = a4.w;
        }
        __syncthreads();
#pragma unroll
        for (int k = 0; k < 32; ++k) {
            float2 wv = *(const float2*)(&sW[k][c2]);
#pragma unroll
            for (int i = 0; i < 4; ++i) {
                float4 a = *(const float4*)(&sA[k][rb + i * 4]);
                acc0[i*4+0] += a.x * wv.x; acc1[i*4+0] += a.x * wv.y;
                acc0[i*4+1] += a.y * wv.x; acc1[i*4+1] += a.y * wv.y;
                acc0[i*4+2] += a.z * wv.x; acc1[i*4+2] += a.z * wv.y;
                acc0[i*4+3] += a.w * wv.x; acc1[i*4+3] += a.w * wv.y;
            }
        }
    }
#pragma unroll
    for (int i = 0; i < 16; ++i) {
        int row = row0 + rb + i;
        if (row < N_NODES) {
            float ndv = nd[row];
            float2 o;
            o.x = acc0[i] * ndv + br[c2];
            o.y = acc1[i] * ndv + br[c2 + 1];
            *(float2*)(A + (size_t)row * OUT_W + c2) = o;
        }
    }
}

// ---------------------------------------------------------------------------
extern "C" void kernel_launch(void* const* d_in, const int* in_sizes, int n_in,
                              void* d_out, int out_size, void* d_ws, size_t ws_size,
                              hipStream_t stream) {
    const float* h    = (const float*)d_in[0];   // [N,128]
    const float* W    = (const float*)d_in[1];   // [5,128,128]
    const float* b    = (const float*)d_in[2];   // [5,128]
    const int*   src  = (const int*)d_in[3];     // int32 per harness contract
    const int*   dst  = (const int*)d_in[4];
    const int*   rate = (const int*)d_in[5];
    float* out = (float*)d_out;                  // [N, 640]

    char* ws = (char*)d_ws;
    int*   deg_out = (int*)(ws + WS_DEG_OUT);
    int*   deg_in  = (int*)(ws + WS_DEG_IN);
    float* nsrc    = (float*)(ws + WS_NSRC);
    float* ndst    = (float*)(ws + WS_NDST);
    int*   offs    = (int*)(ws + WS_OFFS);
    int*   cursor  = (int*)(ws + WS_CURSOR);
    int*   bsum    = (int*)(ws + WS_BSUM);
    int*   packed  = (int*)(ws + WS_PACKED);
    unsigned short* agg = (unsigned short*)(ws + WS_G);

    int n_slots = 0;
    if (ws_size > WS_G) n_slots = (int)((ws_size - WS_G) / SLOT_BYTES);
    if (n_slots > N_RATES) n_slots = N_RATES;

    // degrees + norms (both paths)
    hipMemsetAsync(ws, 0, 0x400000, stream);
    deg_kernel<<<(N_EDGES + 255) / 256, 256, 0, stream>>>(src, dst, rate, deg_out, deg_in);
    norm_kernel<<<(N_RATES * N_NODES + 255) / 256, 256, 0, stream>>>(deg_out, deg_in,
                                                                     nsrc, ndst);

    if (n_slots >= 1) {
        // ---- CSR aggregate-first + MFMA GEMM (no float atomics) ----
        scan1_kernel<<<SCAN_NB, 256, 0, stream>>>(deg_in, offs, bsum);
        scan2_kernel<<<1, 1, 0, stream>>>(bsum);
        scan3_kernel<<<(N_NODES + 255) / 256, 256, 0, stream>>>(offs, bsum, cursor);
        fill_kernel<<<(N_EDGES + 255) / 256, 256, 0, stream>>>(src, dst, rate,
                                                               cursor, packed);
        const int ggrid = (N_NODES * 64 + 255) / 256;   // one wave per dst
        int done = 0;
        while (done < N_RATES) {
            int gs = N_RATES - done; if (gs > n_slots) gs = n_slots;
            switch (gs) {
                case 5: gather_kernel<5, true ><<<ggrid, 256, 0, stream>>>(h, packed, offs,
                                                                           nsrc, agg, done); break;
                case 4: gather_kernel<4, false><<<ggrid, 256, 0, stream>>>(h, packed, offs,
                                                                           nsrc, agg, done); break;
                case 3: gather_kernel<3, false><<<ggrid, 256, 0, stream>>>(h, packed, offs,
                                                                           nsrc, agg, done); break;
                case 2: gather_kernel<2, false><<<ggrid, 256, 0, stream>>>(h, packed, offs,
                                                                           nsrc, agg, done); break;
                default: gather_kernel<1, false><<<ggrid, 256, 0, stream>>>(h, packed, offs,
                                                                            nsrc, agg, done); break;
            }
            gemm_agg_kernel<<<dim3(256, gs), 256, 0, stream>>>(agg, W, b, ndst, out, done);
            done += gs;
        }
    } else {
        // ---- minimal-ws fallback: atomic scatter into out + in-place GEMM ----
        zero_out_kernel<<<(N_NODES * OUT_W / 4 + 255) / 256, 256, 0, stream>>>((float4*)out);
        scatter_c_kernel<<<(N_EDGES / 4 * 64 + 255) / 256, 256, 0, stream>>>(h, src, dst,
                                                                             rate, nsrc, out);
        for (int r = 0; r < N_RATES; ++r)
            gemm_inplace_kernel<<<(N_NODES + 63) / 64, 256, 0, stream>>>(out, W, b, ndst, r);
    }
}

// Round 10
// 952.450 us; speedup vs baseline: 1.0135x; 1.0135x over previous
//
#include <hip/hip_runtime.h>
#include <hip/hip_bf16.h>

#define N_NODES 100000
#define N_EDGES 1600000
#define DIM 128
#define N_RATES 5
#define OUT_W (N_RATES * DIM)          // 640
#define PK_SHIFT 17                     // src < 2^17, rate in bits 17..19
#define PK_MASK  0x1FFFF
#define SCAN_NB ((N_NODES + 1023) / 1024)   // 98
#define MT2_TILES ((N_NODES + 127) / 128)   // 782 (128-row block tiles)
#define GEMM_GX 391                          // 782/391 = exactly 2 tiles/block

// ---- workspace layout (bytes) ----
#define WS_DEG_OUT 0x000000u   // int[5N]  2 MB
#define WS_DEG_IN  0x200000u   // int[5N]  2 MB
#define WS_NSRC    0x400000u   // f32[5N]  2 MB
#define WS_NDST    0x600000u   // f32[5N]  2 MB
#define WS_OFFS    0x800000u   // int[N]   400 KB
#define WS_CURSOR  0x880000u   // int[N]   400 KB
#define WS_BSUM    0x900000u   // int[98]
#define WS_PACKED  0xA00000u   // int[E]   6.4 MB (ends 0x101A800)
#define WS_G       0x1100000u  // agg slots: [slot][N][256] bf16 bits (hi|lo)
#define SLOT_BYTES ((size_t)N_NODES * 256 * sizeof(unsigned short))  // 51.2 MB

typedef float f4     __attribute__((ext_vector_type(4)));
typedef short bf16x8 __attribute__((ext_vector_type(8)));   // 8 bf16 bit-patterns

// ---------------------------------------------------------------------------
// Per-(rate,node) degree histograms (int atomics into zeroed ws).
// ---------------------------------------------------------------------------
__global__ __launch_bounds__(256) void deg_kernel(const int* __restrict__ src,
                                                  const int* __restrict__ dst,
                                                  const int* __restrict__ rate,
                                                  int* __restrict__ deg_out,
                                                  int* __restrict__ deg_in) {
    int e = blockIdx.x * 256 + threadIdx.x;
    if (e >= N_EDGES) return;
    int r = rate[e];
    atomicAdd(&deg_out[r * N_NODES + src[e]], 1);
    atomicAdd(&deg_in [r * N_NODES + dst[e]], 1);
}

// ---------------------------------------------------------------------------
// norm = max(deg,1)^-0.5 for all (rate,node).
// ---------------------------------------------------------------------------
__global__ __launch_bounds__(256) void norm_kernel(const int* __restrict__ deg_out,
                                                   const int* __restrict__ deg_in,
                                                   float* __restrict__ nsrc,
                                                   float* __restrict__ ndst) {
    int i = blockIdx.x * 256 + threadIdx.x;
    if (i >= N_RATES * N_NODES) return;
    int d0 = deg_out[i]; if (d0 < 1) d0 = 1;
    int d1 = deg_in[i];  if (d1 < 1) d1 = 1;
    nsrc[i] = 1.0f / sqrtf((float)d0);
    ndst[i] = 1.0f / sqrtf((float)d1);
}

// ---------------------------------------------------------------------------
// Exclusive scan of per-dst total in-degree (sum over 5 rate rows of deg_in).
// ---------------------------------------------------------------------------
__global__ __launch_bounds__(256) void scan1_kernel(const int* __restrict__ deg_in,
                                                    int* __restrict__ offs,
                                                    int* __restrict__ bsum) {
    __shared__ int sh[256];
    int tid = threadIdx.x;
    int base = blockIdx.x * 1024 + tid * 4;
    int v[4];
#pragma unroll
    for (int j = 0; j < 4; ++j) {
        int idx = base + j, s = 0;
        if (idx < N_NODES) {
#pragma unroll
            for (int r = 0; r < N_RATES; ++r) s += deg_in[r * N_NODES + idx];
        }
        v[j] = s;
    }
    int tsum = v[0] + v[1] + v[2] + v[3];
    sh[tid] = tsum;
    __syncthreads();
    for (int off = 1; off < 256; off <<= 1) {
        int t = (tid >= off) ? sh[tid - off] : 0;
        __syncthreads();
        sh[tid] += t;
        __syncthreads();
    }
    int excl = sh[tid] - tsum;
#pragma unroll
    for (int j = 0; j < 4; ++j) {
        int idx = base + j;
        if (idx < N_NODES) offs[idx] = excl;
        excl += v[j];
    }
    if (tid == 255) bsum[blockIdx.x] = sh[255];
}

__global__ void scan2_kernel(int* __restrict__ bsum) {
    if (threadIdx.x != 0 || blockIdx.x != 0) return;
    int run = 0;
    for (int i = 0; i < SCAN_NB; ++i) { int t = bsum[i]; bsum[i] = run; run += t; }
}

__global__ __launch_bounds__(256) void scan3_kernel(int* __restrict__ offs,
                                                    const int* __restrict__ bsum,
                                                    int* __restrict__ cursor) {
    int i = blockIdx.x * 256 + threadIdx.x;
    if (i >= N_NODES) return;
    int v = offs[i] + bsum[i >> 10];
    offs[i] = v;
    cursor[i] = v;
}

// ---------------------------------------------------------------------------
// CSR fill: packed[pos] = src | (rate<<17), bucketed by dst via atomic cursor.
// ---------------------------------------------------------------------------
__global__ __launch_bounds__(256) void fill_kernel(const int* __restrict__ src,
                                                   const int* __restrict__ dst,
                                                   const int* __restrict__ rate,
                                                   int* __restrict__ cursor,
                                                   int* __restrict__ packed) {
    int e = blockIdx.x * 256 + threadIdx.x;
    if (e >= N_EDGES) return;
    int pos = atomicAdd(&cursor[dst[e]], 1);
    packed[pos] = src[e] | (rate[e] << PK_SHIFT);
}

// ---------------------------------------------------------------------------
// Gather (aggregate-first): one wave per dst, unroll-8 load/accumulate split
// (8 independent h-row loads in flight per step -> latency hiding).
// acc[r] += h[src]*nsrc[r][src]; epilogue stores bf16 hi|lo planes.
// ---------------------------------------------------------------------------
template<int GS, bool ALL>
__global__ __launch_bounds__(256) void gather_kernel(const float* __restrict__ h,
                                                     const int* __restrict__ packed,
                                                     const int* __restrict__ offs,
                                                     const float* __restrict__ nsrc,
                                                     unsigned short* __restrict__ agg,
                                                     int rbase) {
    int gw   = (blockIdx.x * 256 + threadIdx.x) >> 6;  // wave id == dst
    int lane = threadIdx.x & 63;
    if (gw >= N_NODES) return;
    const int d = gw;
    int beg = offs[d];
    int end = (d == N_NODES - 1) ? N_EDGES : offs[d + 1];

    float2 a0 = make_float2(0.f, 0.f), a1 = a0, a2 = a0, a3 = a0, a4 = a0;

    int p = beg;
    for (; p + 8 <= end; p += 8) {
        int pk[8]; int rl[8]; bool use[8]; float2 v[8]; float ns[8];
#pragma unroll
        for (int i = 0; i < 8; ++i) pk[i] = packed[p + i];
#pragma unroll
        for (int i = 0; i < 8; ++i) {
            rl[i]  = (pk[i] >> PK_SHIFT) - rbase;
            use[i] = ALL || ((unsigned)rl[i] < (unsigned)GS);
        }
#pragma unroll
        for (int i = 0; i < 8; ++i) {
            int s = pk[i] & PK_MASK;
            if (use[i]) {
                v[i]  = *(const float2*)(h + (size_t)s * DIM + lane * 2);
                ns[i] = nsrc[(size_t)(rl[i] + rbase) * N_NODES + s];
            }
        }
#pragma unroll
        for (int i = 0; i < 8; ++i) {
            if (!use[i]) continue;
            float tx = v[i].x * ns[i], ty = v[i].y * ns[i];
            switch (rl[i]) {
                case 0: a0.x += tx; a0.y += ty; break;
                case 1: if constexpr (GS > 1) { a1.x += tx; a1.y += ty; } break;
                case 2: if constexpr (GS > 2) { a2.x += tx; a2.y += ty; } break;
                case 3: if constexpr (GS > 3) { a3.x += tx; a3.y += ty; } break;
                default: if constexpr (GS > 4) { a4.x += tx; a4.y += ty; } break;
            }
        }
    }
    for (; p < end; ++p) {
        int pkx = packed[p];
        int rlx = (pkx >> PK_SHIFT) - rbase;
        if (!ALL && (unsigned)rlx >= (unsigned)GS) continue;
        int s = pkx & PK_MASK;
        float2 v = *(const float2*)(h + (size_t)s * DIM + lane * 2);
        float ns = nsrc[(size_t)(rlx + rbase) * N_NODES + s];
        float tx = v.x * ns, ty = v.y * ns;
        switch (rlx) {
            case 0: a0.x += tx; a0.y += ty; break;
            case 1: if constexpr (GS > 1) { a1.x += tx; a1.y += ty; } break;
            case 2: if constexpr (GS > 2) { a2.x += tx; a2.y += ty; } break;
            case 3: if constexpr (GS > 3) { a3.x += tx; a3.y += ty; } break;
            default: if constexpr (GS > 4) { a4.x += tx; a4.y += ty; } break;
        }
    }

    // epilogue: split each f32 into bf16 hi (RNE) + bf16 lo (x - hi)
#pragma unroll
    for (int ri = 0; ri < GS; ++ri) {
        float2 acc = (ri == 0) ? a0 : (ri == 1) ? a1 : (ri == 2) ? a2
                   : (ri == 3) ? a3 : a4;
        unsigned short* row = agg + ((size_t)ri * N_NODES + d) * 256;
        __bf16 hx = (__bf16)acc.x; __bf16 lx = (__bf16)(acc.x - (float)hx);
        __bf16 hy = (__bf16)acc.y; __bf16 ly = (__bf16)(acc.y - (float)hy);
        unsigned int hv = (unsigned int)__builtin_bit_cast(unsigned short, hx)
                        | ((unsigned int)__builtin_bit_cast(unsigned short, hy) << 16);
        unsigned int lv = (unsigned int)__builtin_bit_cast(unsigned short, lx)
                        | ((unsigned int)__builtin_bit_cast(unsigned short, ly) << 16);
        *(unsigned int*)(row + lane * 2)       = hv;
        *(unsigned int*)(row + 128 + lane * 2) = lv;
    }
}

// ---------------------------------------------------------------------------
// MFMA GEMM v2: out[:, r*128:(r+1)*128] = (agg[r] @ W[r]) * nd[r] + b[r]
// Fix vs v1 (318us, MfmaUtil 6%, 2.1e7 bank conflicts):
//  - FRAGMENT-PACKED LDS: sB[ks][nt][plane][lane][8]; B-read = base+lane*16
//    -> linear, conflict-free (v1's [n][k] pitch 68 dwords = 8-way conflict).
//  - MREP=2: two 16-row A-frags share each B-read -> 32 ds_reads/tile (was 64),
//    6 MFMAs per 2 LDS reads.
// Layouts (16x16x32_bf16, harness-verified in R9): A row=l&15, k=(l>>4)*8+j;
// B col=l&15 same k; D col=l&15, row=(l>>4)*4+q.
// ---------------------------------------------------------------------------
__global__ __launch_bounds__(256) void gemm_agg_kernel(const unsigned short* __restrict__ agg,
                                                       const float* __restrict__ Wall,
                                                       const float* __restrict__ bias,
                                                       const float* __restrict__ ndst,
                                                       float* __restrict__ out,
                                                       int rbase) {
    __shared__ __align__(16) unsigned short sB[4][8][2][64][8];   // 64 KB frag-packed
    const int slot = blockIdx.y;
    const int r = rbase + slot;
    const float* Wr = Wall + (size_t)r * DIM * DIM;
    const int tid = threadIdx.x;

    // stage W[r] -> fragment-packed hi/lo: element (k,col) -> sB[k>>5][col>>4]
    //   [p][ (k&31)>>3 *16 + (col&15) ][ k&7 ]
#pragma unroll
    for (int phase = 0; phase < 16; ++phase) {
        int f = phase * 1024 + tid * 4;      // f = k*128 + n, n multiple of 4
        int k = f >> 7, n = f & 127;
        float4 w4 = *(const float4*)(Wr + f);
        int ks = k >> 5;
        int lhi16 = ((k & 31) >> 3) * 16;
        int j = k & 7;
        float wv[4] = {w4.x, w4.y, w4.z, w4.w};
#pragma unroll
        for (int j4 = 0; j4 < 4; ++j4) {
            int col = n + j4;
            int nt = col >> 4;
            int lanew = lhi16 + (col & 15);
            __bf16 hb = (__bf16)wv[j4];
            __bf16 lb = (__bf16)(wv[j4] - (float)hb);
            sB[ks][nt][0][lanew][j] = __builtin_bit_cast(unsigned short, hb);
            sB[ks][nt][1][lanew][j] = __builtin_bit_cast(unsigned short, lb);
        }
    }
    __syncthreads();

    const int w = tid >> 6, l = tid & 63;
    const int lrow = l & 15;            // A row / B col / D col within tile
    const int lk   = (l >> 4) * 8;      // K offset within 32-chunk
    const int lq4  = (l >> 4) * 4;      // D row group
    const float* ndr = ndst + (size_t)r * N_NODES;
    const float* br  = bias + (size_t)r * DIM;

    for (int mt = blockIdx.x; mt < MT2_TILES; mt += GEMM_GX) {
        int rowA0 = mt * 128 + w * 32 + lrow;
        int rowA1 = rowA0 + 16;
        int r0c = rowA0 < N_NODES ? rowA0 : 0;   // clamp; garbage masked at store
        int r1c = rowA1 < N_NODES ? rowA1 : 0;
        const unsigned short* a0p = agg + ((size_t)slot * N_NODES + r0c) * 256;
        const unsigned short* a1p = agg + ((size_t)slot * N_NODES + r1c) * 256;

        f4 acc0[8], acc1[8];
#pragma unroll
        for (int i = 0; i < 8; ++i) { acc0[i] = (f4){0.f,0.f,0.f,0.f}; acc1[i] = acc0[i]; }

#pragma unroll
        for (int ks = 0; ks < 4; ++ks) {
            int k0 = ks * 32 + lk;
            bf16x8 a0h = *(const bf16x8*)(a0p + k0);
            bf16x8 a0l = *(const bf16x8*)(a0p + 128 + k0);
            bf16x8 a1h = *(const bf16x8*)(a1p + k0);
            bf16x8 a1l = *(const bf16x8*)(a1p + 128 + k0);
#pragma unroll
            for (int nt = 0; nt < 8; ++nt) {
                bf16x8 bh = *(const bf16x8*)&sB[ks][nt][0][l][0];
                bf16x8 bl = *(const bf16x8*)&sB[ks][nt][1][l][0];
                acc0[nt] = __builtin_amdgcn_mfma_f32_16x16x32_bf16(a0h, bh, acc0[nt], 0, 0, 0);
                acc0[nt] = __builtin_amdgcn_mfma_f32_16x16x32_bf16(a0h, bl, acc0[nt], 0, 0, 0);
                acc0[nt] = __builtin_amdgcn_mfma_f32_16x16x32_bf16(a0l, bh, acc0[nt], 0, 0, 0);
                acc1[nt] = __builtin_amdgcn_mfma_f32_16x16x32_bf16(a1h, bh, acc1[nt], 0, 0, 0);
                acc1[nt] = __builtin_amdgcn_mfma_f32_16x16x32_bf16(a1h, bl, acc1[nt], 0, 0, 0);
                acc1[nt] = __builtin_amdgcn_mfma_f32_16x16x32_bf16(a1l, bh, acc1[nt], 0, 0, 0);
            }
        }

        int rowD0 = mt * 128 + w * 32 + lq4;
#pragma unroll
        for (int half = 0; half < 2; ++half) {
#pragma unroll
            for (int q = 0; q < 4; ++q) {
                int row = rowD0 + half * 16 + q;
                if (row < N_NODES) {
                    float ndv = ndr[row];
                    float* orow = out + (size_t)row * OUT_W + r * DIM;
#pragma unroll
                    for (int nt = 0; nt < 8; ++nt) {
                        int col = nt * 16 + lrow;
                        f4 a = half ? acc1[nt] : acc0[nt];
                        orow[col] = a[q] * ndv + br[col];
                    }
                }
            }
        }
    }
}

// ===========================================================================
// Minimal-ws fallback (needs only 8 MB): scatter h*ns into out (atomics),
// then in-place per-tile f32 GEMM with norm+bias epilogue.
// ===========================================================================
__global__ __launch_bounds__(256) void zero_out_kernel(float4* __restrict__ out) {
    int i = blockIdx.x * 256 + threadIdx.x;
    if (i < N_NODES * OUT_W / 4) out[i] = make_float4(0.f, 0.f, 0.f, 0.f);
}

__global__ __launch_bounds__(256) void scatter_c_kernel(const float* __restrict__ h,
                                                        const int* __restrict__ src,
                                                        const int* __restrict__ dst,
                                                        const int* __restrict__ rate,
                                                        const float* __restrict__ nsrc,
                                                        float* __restrict__ out) {
    int lane = threadIdx.x & 63;
    int gw = (blockIdx.x * 256 + threadIdx.x) >> 6;
    int e0 = gw * 4;
#pragma unroll
    for (int i = 0; i < 4; ++i) {
        int e = e0 + i;
        if (e >= N_EDGES) return;
        int s = src[e], d = dst[e], r = rate[e];
        float ns = nsrc[(size_t)r * N_NODES + s];
        float2 v = *(const float2*)(h + (size_t)s * DIM + lane * 2);
        float* o = out + (size_t)d * OUT_W + r * DIM + lane * 2;
        unsafeAtomicAdd(o,     v.x * ns);
        unsafeAtomicAdd(o + 1, v.y * ns);
    }
}

__global__ __launch_bounds__(256) void gemm_inplace_kernel(float* __restrict__ outp,
                                                           const float* __restrict__ Wall,
                                                           const float* __restrict__ bias,
                                                           const float* __restrict__ ndst,
                                                           int r) {
    __shared__ float sW[32][128];
    __shared__ float sA[32][64];
    float* A = outp + r * DIM;
    const float* Wr = Wall + (size_t)r * DIM * DIM;
    const float* nd = ndst + (size_t)r * N_NODES;
    const float* br = bias + (size_t)r * DIM;
    int tid  = threadIdx.x;
    int row0 = blockIdx.x * 64;
    int c2   = (tid & 63) * 2;
    int rg   = tid >> 6;
    int rb   = rg * 16;
    float acc0[16], acc1[16];
#pragma unroll
    for (int i = 0; i < 16; ++i) { acc0[i] = 0.f; acc1[i] = 0.f; }
    for (int kc = 0; kc < 128; kc += 32) {
        __syncthreads();
#pragma unroll
        for (int j = 0; j < 4; ++j) {
            int f = tid * 4 + j * 1024;
            int kl = f >> 7, c = f & 127;
            *(float4*)(&sW[kl][c]) = *(const float4*)(Wr + (kc + kl) * 128 + c);
        }
#pragma unroll
        for (int j = 0; j < 2; ++j) {
            int f = tid * 4 + j * 1024;
            int rowl = f >> 5, kl = f & 31;
            int grow = row0 + rowl;
            float4 a4 = make_float4(0.f, 0.f, 0.f, 0.f);
            if (grow < N_NODES) a4 = *(const float4*)(A + (size_t)grow * OUT_W + kc + kl);
            sA[kl + 0][rowl] = a4.x; sA[kl + 1][rowl] = a4.y;
            sA[kl + 2][rowl] = a4.z; sA[kl + 3][rowl] = a4.w;
        }
        __syncthreads();
#pragma unroll
        for (int k = 0; k < 32; ++k) {
            float2 wv = *(const float2*)(&sW[k][c2]);
#pragma unroll
            for (int i = 0; i < 4; ++i) {
                float4 a = *(const float4*)(&sA[k][rb + i * 4]);
                acc0[i*4+0] += a.x * wv.x; acc1[i*4+0] += a.x * wv.y;
                acc0[i*4+1] += a.y * wv.x; acc1[i*4+1] += a.y * wv.y;
                acc0[i*4+2] += a.z * wv.x; acc1[i*4+2] += a.z * wv.y;
                acc0[i*4+3] += a.w * wv.x; acc1[i*4+3] += a.w * wv.y;
            }
        }
    }
#pragma unroll
    for (int i = 0; i < 16; ++i) {
        int row = row0 + rb + i;
        if (row < N_NODES) {
            float ndv = nd[row];
            float2 o;
            o.x = acc0[i] * ndv + br[c2];
            o.y = acc1[i] * ndv + br[c2 + 1];
            *(float2*)(A + (size_t)row * OUT_W + c2) = o;
        }
    }
}

// ---------------------------------------------------------------------------
extern "C" void kernel_launch(void* const* d_in, const int* in_sizes, int n_in,
                              void* d_out, int out_size, void* d_ws, size_t ws_size,
                              hipStream_t stream) {
    const float* h    = (const float*)d_in[0];   // [N,128]
    const float* W    = (const float*)d_in[1];   // [5,128,128]
    const float* b    = (const float*)d_in[2];   // [5,128]
    const int*   src  = (const int*)d_in[3];     // int32 per harness contract
    const int*   dst  = (const int*)d_in[4];
    const int*   rate = (const int*)d_in[5];
    float* out = (float*)d_out;                  // [N, 640]

    char* ws = (char*)d_ws;
    int*   deg_out = (int*)(ws + WS_DEG_OUT);
    int*   deg_in  = (int*)(ws + WS_DEG_IN);
    float* nsrc    = (float*)(ws + WS_NSRC);
    float* ndst    = (float*)(ws + WS_NDST);
    int*   offs    = (int*)(ws + WS_OFFS);
    int*   cursor  = (int*)(ws + WS_CURSOR);
    int*   bsum    = (int*)(ws + WS_BSUM);
    int*   packed  = (int*)(ws + WS_PACKED);
    unsigned short* agg = (unsigned short*)(ws + WS_G);

    int n_slots = 0;
    if (ws_size > WS_G) n_slots = (int)((ws_size - WS_G) / SLOT_BYTES);
    if (n_slots > N_RATES) n_slots = N_RATES;

    // degrees + norms (both paths)
    hipMemsetAsync(ws, 0, 0x400000, stream);
    deg_kernel<<<(N_EDGES + 255) / 256, 256, 0, stream>>>(src, dst, rate, deg_out, deg_in);
    norm_kernel<<<(N_RATES * N_NODES + 255) / 256, 256, 0, stream>>>(deg_out, deg_in,
                                                                     nsrc, ndst);

    if (n_slots >= 1) {
        // ---- CSR aggregate-first + MFMA GEMM (no float atomics) ----
        scan1_kernel<<<SCAN_NB, 256, 0, stream>>>(deg_in, offs, bsum);
        scan2_kernel<<<1, 1, 0, stream>>>(bsum);
        scan3_kernel<<<(N_NODES + 255) / 256, 256, 0, stream>>>(offs, bsum, cursor);
        fill_kernel<<<(N_EDGES + 255) / 256, 256, 0, stream>>>(src, dst, rate,
                                                               cursor, packed);
        const int ggrid = (N_NODES * 64 + 255) / 256;   // one wave per dst
        int done = 0;
        while (done < N_RATES) {
            int gs = N_RATES - done; if (gs > n_slots) gs = n_slots;
            switch (gs) {
                case 5: gather_kernel<5, true ><<<ggrid, 256, 0, stream>>>(h, packed, offs,
                                                                           nsrc, agg, done); break;
                case 4: gather_kernel<4, false><<<ggrid, 256, 0, stream>>>(h, packed, offs,
                                                                           nsrc, agg, done); break;
                case 3: gather_kernel<3, false><<<ggrid, 256, 0, stream>>>(h, packed, offs,
                                                                           nsrc, agg, done); break;
                case 2: gather_kernel<2, false><<<ggrid, 256, 0, stream>>>(h, packed, offs,
                                                                           nsrc, agg, done); break;
                default: gather_kernel<1, false><<<ggrid, 256, 0, stream>>>(h, packed, offs,
                                                                            nsrc, agg, done); break;
            }
            gemm_agg_kernel<<<dim3(GEMM_GX, gs), 256, 0, stream>>>(agg, W, b, ndst, out, done);
            done += gs;
        }
    } else {
        // ---- minimal-ws fallback: atomic scatter into out + in-place GEMM ----
        zero_out_kernel<<<(N_NODES * OUT_W / 4 + 255) / 256, 256, 0, stream>>>((float4*)out);
        scatter_c_kernel<<<(N_EDGES / 4 * 64 + 255) / 256, 256, 0, stream>>>(h, src, dst,
                                                                             rate, nsrc, out);
        for (int r = 0; r < N_RATES; ++r)
            gemm_inplace_kernel<<<(N_NODES + 63) / 64, 256, 0, stream>>>(out, W, b, ndst, r);
    }
}